// Round 9
// baseline (662.677 us; speedup 1.0000x reference)
//
#include <hip/hip_runtime.h>
#include <hip/hip_bf16.h>

typedef __attribute__((ext_vector_type(8))) short short8;
typedef __attribute__((ext_vector_type(4))) float f32x4;
typedef __attribute__((ext_vector_type(16))) float f32x16;

#define GLOAD_LDS16(gp, lp)                                                      \
  __builtin_amdgcn_global_load_lds(                                              \
      (const __attribute__((address_space(1))) void*)(gp),                       \
      (__attribute__((address_space(3))) void*)(lp), 16, 0, 0)

#define SBAR() asm volatile("s_barrier" ::: "memory")
#define VMC(n)                                                                   \
  do {                                                                           \
    asm volatile("s_waitcnt vmcnt(" #n ")" ::: "memory");                        \
    __builtin_amdgcn_sched_barrier(0);                                           \
  } while (0)

__device__ __forceinline__ unsigned short f2bf_rne(float f) {
  union { float f; unsigned int u; } v; v.f = f;
  unsigned int u = v.u;
  u += 0x7fffu + ((u >> 16) & 1u);
  return (unsigned short)(u >> 16);
}

// ---------------------------------------------------------------- convert ----
__global__ void cvt_f32_bf16(const float* __restrict__ src,
                             unsigned short* __restrict__ dst, int n8) {
  int i = blockIdx.x * blockDim.x + threadIdx.x;
  int stride = gridDim.x * blockDim.x;
  const f32x4* s4 = (const f32x4*)src;
  short8* d8 = (short8*)dst;
  for (; i < n8; i += stride) {
    f32x4 a = s4[2 * i], b = s4[2 * i + 1];
    short8 o;
    o[0] = (short)f2bf_rne(a[0]); o[1] = (short)f2bf_rne(a[1]);
    o[2] = (short)f2bf_rne(a[2]); o[3] = (short)f2bf_rne(a[3]);
    o[4] = (short)f2bf_rne(b[0]); o[5] = (short)f2bf_rne(b[1]);
    o[6] = (short)f2bf_rne(b[2]); o[7] = (short)f2bf_rne(b[3]);
    d8[i] = o;
  }
}

// ------------------------------------------------- T = mask * 2 * (x @ A^T) ---
__global__ __launch_bounds__(256) void lora_t_kernel(
    const unsigned short* __restrict__ xb,
    const unsigned short* __restrict__ Ab,
    const int* __restrict__ offs,
    unsigned short* __restrict__ T)
{
  __shared__ unsigned short xs[64 * 64];
  __shared__ unsigned short as_[32 * 64];
  const int t = threadIdx.x;
  const int m0 = blockIdx.x * 64;
  const int l = t & 63, w = t >> 6;
  const int lr = l & 15, lk = (l >> 4) * 8;
  const int arow = t >> 3, acol = (t & 7) * 8;
  f32x4 acc0 = {0, 0, 0, 0}, acc1 = {0, 0, 0, 0};
  for (int kt = 0; kt < 64; ++kt) {
    __syncthreads();
    const int kof = kt * 64 + acol;
    GLOAD_LDS16(xb + (size_t)(m0 + arow) * 4096 + kof,      (char*)xs + (arow * 64 + acol) * 2);
    GLOAD_LDS16(xb + (size_t)(m0 + 32 + arow) * 4096 + kof, (char*)xs + ((32 + arow) * 64 + acol) * 2);
    GLOAD_LDS16(Ab + (size_t)arow * 4096 + kof,             (char*)as_ + (arow * 64 + acol) * 2);
    __syncthreads();
#pragma unroll
    for (int kk = 0; kk < 2; ++kk) {
      short8 a  = *(const short8*)&xs[(w * 16 + lr) * 64 + kk * 32 + lk];
      short8 b0 = *(const short8*)&as_[lr * 64 + kk * 32 + lk];
      short8 b1 = *(const short8*)&as_[(16 + lr) * 64 + kk * 32 + lk];
      acc0 = __builtin_amdgcn_mfma_f32_16x16x32_bf16(a, b0, acc0, 0, 0, 0);
      acc1 = __builtin_amdgcn_mfma_f32_16x16x32_bf16(a, b1, acc1, 0, 0, 0);
    }
  }
  const int rowb = (l >> 4) * 4;
#pragma unroll
  for (int j = 0; j < 4; ++j) {
    int m = m0 + w * 16 + rowb + j;
    int bb = m >> 12, s = m & 4095;
    int kcut = offs[bb]; if (kcut > 4096) kcut = 4096;
    bool keep = s >= 4096 - kcut;
    T[(size_t)m * 32 + lr]      = keep ? f2bf_rne(2.0f * acc0[j]) : (unsigned short)0;
    T[(size_t)m * 32 + 16 + lr] = keep ? f2bf_rne(2.0f * acc1[j]) : (unsigned short)0;
  }
}

// ------------------------------------------------------------- main GEMM -----
// 256x256 tile, BK=64, 2 LDS slots, 8 waves, quarter-wave swizzle (verified
// zero conflicts).  NEW: mfma_f32_32x32x16_bf16 (pipe 2495 vs 2075 TF, half
// the MFMA instructions).  Wave tile 64 rows x 128 cols = A-frags 2x32rows,
// B-frags 2qc x 2j x 32cols; 4 phases per K-tile (one per K=16 step):
// {2 A-reads + 4 B-reads; stage; barrier; 8 MFMA; [VMC(0) at P3]; barrier}.
// Operand layout (analog of verified 16x16): lane=row(l&31), K-half=l>>5.
// C/D (m74/m101-verified): col=lane&31, row=(reg&3)+8*(reg>>2)+4*(lane>>5).
__global__ __launch_bounds__(512, 2) void gemm_kernel(
    const unsigned short* __restrict__ xb,   // [16384][4096] bf16
    const unsigned short* __restrict__ Wb,   // [4096][4096]  bf16
    const unsigned short* __restrict__ Tm,   // [16384][32]   bf16 (mask+scale)
    const unsigned short* __restrict__ Bwb,  // [4096][32]    bf16
    const float* __restrict__ bias,          // [4096]
    float* __restrict__ out)                 // [16384][4096] f32
{
  constexpr int K = 4096;
  extern __shared__ char smem[];             // 128 KiB

  const int bid = blockIdx.x;
  const int swz = (bid & 7) * 128 + (bid >> 3);
  const int m0 = (swz >> 4) * 256;
  const int n0 = (swz & 15) * 256;

  const int t = threadIdx.x;
  const int l = t & 63, w = t >> 6;
  const int wqr = w >> 2;
  const int pr = (w >> 1) & 1;
  const int pc = w & 1;
  const int la = l & 31, ksel = l >> 5;
  const int cxor = la & 7;                   // swizzle XOR on 16B-chunk index

  const int srow = t >> 3;
  const int schunk = ((t & 7) ^ ((t >> 3) & 7)) * 8;
  const unsigned short* pA0 = xb + (size_t)(m0 + srow) * K + schunk;
  const unsigned short* pA1 = xb + (size_t)(m0 + 128 + srow) * K + schunk;
  const unsigned short* pB0 = Wb + (size_t)(n0 + srow) * K + schunk;
  const unsigned short* pB1 = Wb + (size_t)(n0 + 128 + srow) * K + schunk;
  unsigned short* sm = (unsigned short*)smem;
  const int ldst = t * 16;

#define STG(PTR, SLOT, ISB, HALF, KT)                                           \
  do {                                                                          \
    const unsigned short* g_ = (PTR) + (KT) * 64;                               \
    char* d_ = smem + (SLOT) * 65536 + (ISB) * 32768 + (HALF) * 16384 + ldst;   \
    GLOAD_LDS16(g_, d_);                                                        \
    GLOAD_LDS16(g_ + (size_t)64 * K, d_ + 8192);                                \
  } while (0)
#define STGA(SLOT, KT) do { STG(pA0, SLOT, 0, 0, KT); STG(pA1, SLOT, 0, 1, KT); } while (0)
#define STGB(SLOT, KT) do { STG(pB0, SLOT, 1, 0, KT); STG(pB1, SLOT, 1, 1, KT); } while (0)

  const int rowbase = m0 + wqr * 128 + pr * 64;
  const int arowbase = (wqr * 128 + pr * 64) * 64;   // element offset in A region

  f32x16 acc[2][2][2];

  // --- LoRA prestep: register-direct (L2-resident), initializes acc ---
  {
    short8 ta[2][2];
#pragma unroll
    for (int i = 0; i < 2; ++i)
#pragma unroll
      for (int ks = 0; ks < 2; ++ks)
        ta[i][ks] = *(const short8*)(Tm + (size_t)(rowbase + i * 32 + la) * 32 + ks * 16 + ksel * 8);
    const f32x16 z16 = {0.f, 0.f, 0.f, 0.f, 0.f, 0.f, 0.f, 0.f,
                        0.f, 0.f, 0.f, 0.f, 0.f, 0.f, 0.f, 0.f};
#pragma unroll
    for (int qc = 0; qc < 2; ++qc)
#pragma unroll
      for (int j = 0; j < 2; ++j) {
        const unsigned short* bp = Bwb + (size_t)(n0 + qc * 128 + pc * 64 + j * 32 + la) * 32;
        short8 tb0 = *(const short8*)(bp + ksel * 8);
        short8 tb1 = *(const short8*)(bp + 16 + ksel * 8);
#pragma unroll
        for (int i = 0; i < 2; ++i) {
          f32x16 v = __builtin_amdgcn_mfma_f32_32x32x16_bf16(ta[i][0], tb0, z16, 0, 0, 0);
          acc[qc][i][j] = __builtin_amdgcn_mfma_f32_32x32x16_bf16(ta[i][1], tb1, v, 0, 0, 0);
        }
      }
  }

  // prologue: stage tile 0 fully, drain, barrier
  STGA(0, 0); STGB(0, 0);
  VMC(0);
  SBAR();

  // phase = one K=16 step: 6 ds_read_b128 + optional stage + 8 MFMA.
#define PHASE(SLOT, KS, WAIT, ...)                                              \
  {                                                                             \
    const unsigned short* Sb = sm + (SLOT) * 32768;                             \
    const int ck = ((((KS) * 2) + ksel) ^ cxor) * 8;                            \
    short8 afr[2], bfr[2][2];                                                   \
    _Pragma("unroll")                                                           \
    for (int i_ = 0; i_ < 2; ++i_)                                              \
      afr[i_] = *(const short8*)(Sb + arowbase + (i_ * 32 + la) * 64 + ck);     \
    _Pragma("unroll")                                                           \
    for (int q_ = 0; q_ < 2; ++q_)                                              \
      _Pragma("unroll")                                                         \
      for (int j_ = 0; j_ < 2; ++j_)                                            \
        bfr[q_][j_] = *(const short8*)(Sb + 16384 +                             \
            (q_ * 128 + pc * 64 + j_ * 32 + la) * 64 + ck);                     \
    __VA_ARGS__;                                                                \
    SBAR();                                                                     \
    __builtin_amdgcn_s_setprio(1);                                              \
    _Pragma("unroll")                                                           \
    for (int q_ = 0; q_ < 2; ++q_)                                              \
      _Pragma("unroll")                                                         \
      for (int i_ = 0; i_ < 2; ++i_)                                            \
        _Pragma("unroll")                                                       \
        for (int j_ = 0; j_ < 2; ++j_)                                          \
          acc[q_][i_][j_] = __builtin_amdgcn_mfma_f32_32x32x16_bf16(            \
              afr[i_], bfr[q_][j_], acc[q_][i_][j_], 0, 0, 0);                  \
    __builtin_amdgcn_s_setprio(0);                                              \
    WAIT;                                                                       \
    SBAR();                                                                     \
  }

  // windows 0..61: stage t+1 in P0 (A halves) and P1 (B halves); single
  // VMC(0) at P3 (loads were issued >=2 phases earlier -> non-stalling drain).
  for (int I = 0; I < 31; ++I) {
    const int a = 2 * I;
    PHASE(0, 0, ((void)0), STGA(1, a + 1));
    PHASE(0, 1, ((void)0), STGB(1, a + 1));
    PHASE(0, 2, ((void)0), );
    PHASE(0, 3, VMC(0), );
    PHASE(1, 0, ((void)0), STGA(0, a + 2));
    PHASE(1, 1, ((void)0), STGB(0, a + 2));
    PHASE(1, 2, ((void)0), );
    PHASE(1, 3, VMC(0), );
  }
  // window 62: stage tile 63; window 63: bare
  PHASE(0, 0, ((void)0), STGA(1, 63));
  PHASE(0, 1, ((void)0), STGB(1, 63));
  PHASE(0, 2, ((void)0), );
  PHASE(0, 3, VMC(0), );
  PHASE(1, 0, ((void)0), );
  PHASE(1, 1, ((void)0), );
  PHASE(1, 2, ((void)0), );
  PHASE(1, 3, ((void)0), );
#undef PHASE
#undef STGA
#undef STGB
#undef STG

  // epilogue: bias + store.  C/D: col = la, row = (r&3)+8*(r>>2)+4*ksel.
#pragma unroll
  for (int qc = 0; qc < 2; ++qc)
#pragma unroll
    for (int j = 0; j < 2; ++j) {
      const int cb = n0 + qc * 128 + pc * 64 + j * 32;
      const float bvv = bias[cb + la];
#pragma unroll
      for (int i = 0; i < 2; ++i)
#pragma unroll
        for (int r = 0; r < 16; ++r) {
          const int row = rowbase + i * 32 + (r & 3) + 8 * (r >> 2) + 4 * ksel;
          out[(size_t)row * 4096 + cb + la] = acc[qc][i][j][r] + bvv;
        }
    }
}

// ----------------------------------------------------------------- launch ----
extern "C" void kernel_launch(void* const* d_in, const int* in_sizes, int n_in,
                              void* d_out, int out_size, void* d_ws, size_t ws_size,
                              hipStream_t stream) {
  const float* x   = (const float*)d_in[0];
  const int* offs  = (const int*)d_in[1];
  const float* W   = (const float*)d_in[2];
  const float* b   = (const float*)d_in[3];
  const float* A   = (const float*)d_in[4];
  const float* Bw  = (const float*)d_in[5];
  float* out = (float*)d_out;

  char* ws = (char*)d_ws;
  unsigned short* xb  = (unsigned short*)ws;
  unsigned short* Wb  = (unsigned short*)(ws + 134217728);
  unsigned short* Ab  = (unsigned short*)(ws + 167772160);
  unsigned short* Bwb = (unsigned short*)(ws + 168034304);
  unsigned short* T   = (unsigned short*)(ws + 168296448);

  hipFuncSetAttribute((const void*)gemm_kernel,
                      hipFuncAttributeMaxDynamicSharedMemorySize, 131072);

  cvt_f32_bf16<<<2048, 256, 0, stream>>>(x, xb, 67108864 / 8);
  cvt_f32_bf16<<<2048, 256, 0, stream>>>(W, Wb, 16777216 / 8);
  cvt_f32_bf16<<<64, 256, 0, stream>>>(A, Ab, 131072 / 8);
  cvt_f32_bf16<<<64, 256, 0, stream>>>(Bw, Bwb, 131072 / 8);
  lora_t_kernel<<<256, 256, 0, stream>>>(xb, Ab, offs, T);
  gemm_kernel<<<1024, 512, 131072, stream>>>(xb, Wb, T, Bwb, b, out);
}